// Round 1
// baseline (211.182 us; speedup 1.0000x reference)
//
#include <hip/hip_runtime.h>

// EquivariantLinear: out[pos, c, m] = pw * sum_k x[pos, k, m] * W_{l(m)}[k, c]
// pos = 32768, C_IN = C_OUT = 256, FEAT = 9 (irreps 1,3,5), pw = 1/16.
// R3: persistent 256 blocks x 512 threads, 1 block/CU, double-buffered LDS
// (2 x 76032 B), depth-1 cross-tile prefetch (global->reg before compute,
// reg->LDS after the post-compute barrier). Out-stage aliases the consumed
// buffer; staging of tile t+1 goes to the other buffer in the same phase.

typedef float f32x4 __attribute__((ext_vector_type(4)));
typedef short s16x8 __attribute__((ext_vector_type(8)));

#define POSB 16                      // positions per tile
#define XS_KS 264                    // padded k-stride (elems)
#define XS_MS (POSB * XS_KS)         // 4224 elems per m-plane
#define BUF_BYTES (9 * XS_MS * 2)    // 76032 B per x-buffer
#define SMEM_BYTES (2 * BUF_BYTES)   // 152064 B total (1 block/CU)
#define STG_ROW 148                  // out-stage row stride (floats); row=144 used
#define TILES_PER_BLK 8              // 256 blocks x 8 tiles = 2048 tiles

__device__ __forceinline__ unsigned short f2bf(float f) {
  unsigned u = __float_as_uint(f);
  return (unsigned short)((u + 0x7FFFu + ((u >> 16) & 1u)) >> 16);
}

// ---- prep: W^T bf16 image in ws: wt[irr][c][k] = pw * w_irr[k][c] ----
__global__ void prep_w(const float* __restrict__ w0, const float* __restrict__ w1,
                       const float* __restrict__ w2, unsigned short* __restrict__ wt) {
  const int b = blockIdx.x;
  const int irr = b / 16;
  const int tile = b % 16;
  const int k0 = (tile >> 2) << 6;
  const int c0 = (tile & 3) << 6;
  const float* w = (irr == 0) ? w0 : ((irr == 1) ? w1 : w2);
  __shared__ float lt[64 * 65];
  const int t = threadIdx.x;
#pragma unroll
  for (int i = 0; i < 16; ++i) {
    int e = t + (i << 8);
    int kk = e >> 6, cc = e & 63;
    lt[cc * 65 + kk] = w[(k0 + kk) * 256 + (c0 + cc)];
  }
  __syncthreads();
#pragma unroll
  for (int i = 0; i < 16; ++i) {
    int e = t + (i << 8);
    int cc = e >> 6, kk = e & 63;
    wt[irr * 65536 + (c0 + cc) * 256 + (k0 + kk)] = f2bf(lt[cc * 65 + kk] * 0.0625f);
  }
}

// convert one (pos, kquad) unit (36 floats held in 9 f32x4 regs) to bf16 and
// scatter into the 9 m-planes (stride-8B ds_write_b64, conflict-free)
__device__ __forceinline__ void stage_unit(unsigned short* xs, int pos, int kq,
                                           const f32x4* pf) {
#pragma unroll
  for (int m = 0; m < 9; ++m) {
    unsigned long long pk =
        (unsigned long long)f2bf(pf[m >> 2][m & 3]) |
        ((unsigned long long)f2bf(pf[(9 + m) >> 2][(9 + m) & 3]) << 16) |
        ((unsigned long long)f2bf(pf[(18 + m) >> 2][(18 + m) & 3]) << 32) |
        ((unsigned long long)f2bf(pf[(27 + m) >> 2][(27 + m) & 3]) << 48);
    *reinterpret_cast<unsigned long long*>(xs + m * XS_MS + pos * XS_KS + kq) = pk;
  }
}

// ---- main: 256 persistent blocks x 512 threads (8 waves), 1 block/CU ----
__global__ __launch_bounds__(512, 2) void eqlin_main(
    const float* __restrict__ x, const unsigned short* __restrict__ wt,
    float* __restrict__ out) {
  extern __shared__ char smem[];

  const int t = threadIdx.x;

  // two (pos, kquad) staging units per thread
  const int pos0 = t >> 6;           // 0..7
  const int pos1 = pos0 + 8;         // 8..15
  const int kq = (t & 63) << 2;      // k base, multiple of 4
  const int u0 = t * 9;              // f32x4 index of unit0 within a tile
  const int u1 = (t + 512) * 9;

  const f32x4* xg = reinterpret_cast<const f32x4*>(x);

  // wave identity for compute
  const int w = t >> 6;
  const int l = t & 63;
  const int cr = l & 15;          // A row (=pos) / B col (=c in tile)
  const int kg = (l >> 4) << 3;   // k-chunk base 0/8/16/24
  const int c0 = w << 5;          // 32 channels per wave
  const unsigned short* wtB = wt + (c0 + cr) * 256 + kg;

  const long long tile0 = (long long)blockIdx.x * TILES_PER_BLK;

  f32x4 pfA[9], pfB[9];  // in-flight tile (held across compute)

  // ---- prologue: load+stage tile 0 into buf0 ----
  {
    const f32x4* s = xg + tile0 * 9216;
#pragma unroll
    for (int j = 0; j < 9; ++j) pfA[j] = s[u0 + j];
#pragma unroll
    for (int j = 0; j < 9; ++j) pfB[j] = s[u1 + j];
    unsigned short* xs0 = reinterpret_cast<unsigned short*>(smem);
    stage_unit(xs0, pos0, kq, pfA);
    stage_unit(xs0, pos1, kq, pfB);
  }
  __syncthreads();

  for (int it = 0; it < TILES_PER_BLK; ++it) {
    const int p = it & 1;
    const unsigned short* xsb =
        reinterpret_cast<const unsigned short*>(smem + p * BUF_BYTES);

    // A: issue next tile's global loads (consumed after the post-compute
    //    barrier -> HBM latency hides under the MFMA passes)
    if (it + 1 < TILES_PER_BLK) {
      const f32x4* s = xg + (tile0 + it + 1) * 9216;
#pragma unroll
      for (int j = 0; j < 9; ++j) pfA[j] = s[u0 + j];
#pragma unroll
      for (int j = 0; j < 9; ++j) pfB[j] = s[u1 + j];
    }

    // B: compute tile it from buf[p]
    const unsigned short* xsA = xsb + cr * XS_KS + kg;

    f32x4 accA[4][2];  // m = 0..3
#pragma unroll
    for (int m = 0; m < 4; ++m)
#pragma unroll
      for (int ct = 0; ct < 2; ++ct) accA[m][ct] = (f32x4){0.f, 0.f, 0.f, 0.f};

    // pass 1: m 0..3 (irr0 for m0, irr1 for m1..3)
#pragma unroll 2
    for (int ks = 0; ks < 8; ++ks) {
      const int kk = ks << 5;
      s16x8 b00 = *reinterpret_cast<const s16x8*>(wtB + kk);
      s16x8 b01 = *reinterpret_cast<const s16x8*>(wtB + 4096 + kk);
      s16x8 b10 = *reinterpret_cast<const s16x8*>(wtB + 65536 + kk);
      s16x8 b11 = *reinterpret_cast<const s16x8*>(wtB + 65536 + 4096 + kk);
      {
        s16x8 a = *reinterpret_cast<const s16x8*>(xsA + kk);
        accA[0][0] = __builtin_amdgcn_mfma_f32_16x16x32_bf16(a, b00, accA[0][0], 0, 0, 0);
        accA[0][1] = __builtin_amdgcn_mfma_f32_16x16x32_bf16(a, b01, accA[0][1], 0, 0, 0);
      }
#pragma unroll
      for (int m = 1; m < 4; ++m) {
        s16x8 a = *reinterpret_cast<const s16x8*>(xsA + m * XS_MS + kk);
        accA[m][0] = __builtin_amdgcn_mfma_f32_16x16x32_bf16(a, b10, accA[m][0], 0, 0, 0);
        accA[m][1] = __builtin_amdgcn_mfma_f32_16x16x32_bf16(a, b11, accA[m][1], 0, 0, 0);
      }
    }

    f32x4 accB[5][2];  // m = 4..8 (irr2)
#pragma unroll
    for (int m = 0; m < 5; ++m)
#pragma unroll
      for (int ct = 0; ct < 2; ++ct) accB[m][ct] = (f32x4){0.f, 0.f, 0.f, 0.f};

    // pass 2: m 4..8
#pragma unroll 2
    for (int ks = 0; ks < 8; ++ks) {
      const int kk = ks << 5;
      s16x8 b20 = *reinterpret_cast<const s16x8*>(wtB + 2 * 65536 + kk);
      s16x8 b21 = *reinterpret_cast<const s16x8*>(wtB + 2 * 65536 + 4096 + kk);
#pragma unroll
      for (int m = 0; m < 5; ++m) {
        s16x8 a = *reinterpret_cast<const s16x8*>(xsA + (m + 4) * XS_MS + kk);
        accB[m][0] = __builtin_amdgcn_mfma_f32_16x16x32_bf16(a, b20, accB[m][0], 0, 0, 0);
        accB[m][1] = __builtin_amdgcn_mfma_f32_16x16x32_bf16(a, b21, accB[m][1], 0, 0, 0);
      }
    }
    __syncthreads();  // all waves done reading buf[p]; its LDS is reusable

    // C: out-stage tile it via per-wave slice of buf[p] (wave-local sync only)
    float* stgw = reinterpret_cast<float*>(smem + p * BUF_BYTES) + w * (POSB * STG_ROW);
    const int posb = (l >> 4) << 2;
    f32x4* o4 = reinterpret_cast<f32x4*>(out) + (tile0 + it) * 9216 + w * 72;

#pragma unroll
    for (int ct = 0; ct < 2; ++ct) {
      // scatter acc -> stgw[pos][cr*9 + m]  (fp32, ~2-way banks: free)
#pragma unroll
      for (int m = 0; m < 9; ++m) {
#pragma unroll
        for (int j = 0; j < 4; ++j) {
          float v = (m < 4) ? accA[m][ct][j] : accB[m - 4][ct][j];
          stgw[(posb + j) * STG_ROW + cr * 9 + m] = v;
        }
      }
      asm volatile("s_waitcnt lgkmcnt(0)" ::: "memory");
      // coalesced float4 store of this wave's contiguous 16c x 9m slice
#pragma unroll
      for (int q = 0; q < 9; ++q) {
        const int e = l + (q << 6);                 // 0..575 float4s
        const int pos = (int)((unsigned)e / 36u);
        const int rem = e - pos * 36;
        f32x4 v = *reinterpret_cast<const f32x4*>(stgw + pos * STG_ROW + (rem << 2));
        o4[pos * 576 + ct * 36 + rem] = v;
      }
      asm volatile("s_waitcnt lgkmcnt(0)" ::: "memory");  // drain reads before next ct writes
    }

    // D: convert+stage the prefetched tile into the other buffer (disjoint
    //    from the out-stage slice region of buf[p])
    if (it + 1 < TILES_PER_BLK) {
      unsigned short* xsn = reinterpret_cast<unsigned short*>(smem + (p ^ 1) * BUF_BYTES);
      stage_unit(xsn, pos0, kq, pfA);
      stage_unit(xsn, pos1, kq, pfB);
    }
    __syncthreads();  // buf[p^1] ready for next iter; out-stage slices drained
  }
}

extern "C" void kernel_launch(void* const* d_in, const int* in_sizes, int n_in,
                              void* d_out, int out_size, void* d_ws, size_t ws_size,
                              hipStream_t stream) {
  const float* x = (const float*)d_in[0];
  const float* w0 = (const float*)d_in[1];
  const float* w1 = (const float*)d_in[2];
  const float* w2 = (const float*)d_in[3];
  unsigned short* wt = (unsigned short*)d_ws;  // 3*256*256 bf16 = 384 KB
  float* out = (float*)d_out;

  prep_w<<<48, 256, 0, stream>>>(w0, w1, w2, wt);

  (void)hipFuncSetAttribute(reinterpret_cast<const void*>(eqlin_main),
                            hipFuncAttributeMaxDynamicSharedMemorySize, SMEM_BYTES);
  eqlin_main<<<256, 512, SMEM_BYTES, stream>>>(x, wt, out);
}